// Round 9
// baseline (4396.264 us; speedup 1.0000x reference)
//
#include <hip/hip_runtime.h>
#include <hip/hip_fp16.h>
#include <stdint.h>

#define B_TOTAL 1024
#define T_TOTAL 1024
#define LOG2E 1.44269504088896f

typedef _Float16 f16x2 __attribute__((ext_vector_type(2)));
typedef _Float16 f16x8 __attribute__((ext_vector_type(8)));
typedef float    f32x4 __attribute__((ext_vector_type(4)));

__device__ __forceinline__ uint32_t packf2(float a, float b) {
    f16x2 t;
    t.x = (_Float16)a;
    t.y = (_Float16)b;
    return __builtin_bit_cast(uint32_t, t);
}

__device__ __forceinline__ float sigm_(float z) {
    float e = __builtin_amdgcn_exp2f(-LOG2E * z);
    return __builtin_amdgcn_rcpf(1.0f + e);
}
__device__ __forceinline__ float tanh_(float z) {
    float e = __builtin_amdgcn_exp2f((2.0f * LOG2E) * z);
    float r = __builtin_amdgcn_rcpf(1.0f + e);
    return __builtin_fmaf(-2.0f, r, 1.0f);
}

__device__ __forceinline__ void wavebar() {
#if __has_builtin(__builtin_amdgcn_wave_barrier)
    __builtin_amdgcn_wave_barrier();
#endif
}

__device__ __forceinline__ f32x4 mfma16(f16x8 a, f16x8 b, f32x4 c) {
    return __builtin_amdgcn_mfma_f32_16x16x32_f16(a, b, c, 0, 0, 0);
}

// MFMA LSTM scan. One wave = 16 same-direction chains (batches).
// gates[16 chains][4 gates x units] = x.Wih^T + h.Whh^T via 16x16x32 f16 MFMA:
//   A-frag (lane: m=lane&15, k=quad*8+e) = activations (LDS-staged x; h from hA)
//   B-frag (lane: n=lane&15, k=quad*8+e) = weights, resident in VGPRs, padded 0
//   C-frag (lane: col=lane&15=unit, row=quad*4+reg=chain), one acc per (gate, ut)
//   -> all 4 gates of (chain,unit) land in the SAME lane, same reg slot: no
//      gate exchange; the A-frag read IS the h all-gather (1 ds_read_b128).
// Bias pre-splatted into acc init. x staged 2 steps ahead into a 4-buffer LDS
// ring (no h dependency). No __syncthreads anywhere (1 wave/block, lockstep).
template <int D, int H, bool LAYER1, bool STORE_ALL>
__global__ void __launch_bounds__(64, 1) lstm_mfma(
    const float* __restrict__ x,              // LAYER1: [B][T][8] f32
    const __half* __restrict__ inbuf,         // else:   [T][B][D] f16
    const float* __restrict__ wihf, const float* __restrict__ whhf,
    const float* __restrict__ bihf, const float* __restrict__ bhhf,
    const float* __restrict__ wihb, const float* __restrict__ whhb,
    const float* __restrict__ bihb, const float* __restrict__ bhhb,
    __half* __restrict__ outbuf,              // STORE_ALL: [T][B][2H] f16
    float* __restrict__ lasth)                // !STORE_ALL: [B][H] f32
{
    constexpr int UT = (H + 15) / 16;         // unit tiles (N)
    constexpr int KT = (D + 31) / 32;         // K tiles for x (L1: D=16 -> 1)
    constexpr int XP = KT * 32;               // padded x row (halves)

    const int dir  = blockIdx.y;
    const int l    = threadIdx.x;
    const int quad = l >> 4;
    const int ln   = l & 15;
    const int b0   = blockIdx.x * 16;
    const int sgn  = dir ? -1 : 1;
    const int tt0  = dir ? (T_TOTAL - 1) : 0;

    const float* w_ih = dir ? wihb : wihf;
    const float* w_hh = dir ? whhb : whhf;
    const float* b_ih = dir ? bihb : bihf;
    const float* b_hh = dir ? bhhb : bhhf;

    __shared__ __align__(16) __half hA[16][32];        // h[chain][unit], pad 0
    __shared__ __align__(16) __half xA[4][16][XP];     // staged x rows, pad 0

    // ---- zero LDS (pads must stay 0 forever) ----
    {
        uint32_t* z1 = (uint32_t*)&hA[0][0];
#pragma unroll
        for (int i = 0; i < (16 * 32 / 2) / 64; ++i) z1[l + 64 * i] = 0u;
        uint32_t* z2 = (uint32_t*)&xA[0][0][0];
        constexpr int ZN = 4 * 16 * XP / 2;
#pragma unroll
        for (int i = 0; i < ZN / 64; ++i) z2[l + 64 * i] = 0u;
    }
    wavebar();

    // ---- weight B-fragments -> VGPRs (one-time), zero-padded ----
    f16x8 Bx[4][UT][KT];
    f16x8 Bh[4][UT];
    float bias[4][UT];
#pragma unroll
    for (int q = 0; q < 4; ++q) {
#pragma unroll
        for (int ut = 0; ut < UT; ++ut) {
            const int u  = ut * 16 + ln;
            const bool uv = (u < H);
            const int r  = q * H + (uv ? u : 0);
#pragma unroll
            for (int kt = 0; kt < KT; ++kt) {
#pragma unroll
                for (int e = 0; e < 8; ++e) {
                    const int kg = kt * 32 + quad * 8 + e;
                    const float wv = (uv && kg < D) ? w_ih[r * D + kg] : 0.0f;
                    Bx[q][ut][kt][e] = (_Float16)wv;
                }
            }
#pragma unroll
            for (int e = 0; e < 8; ++e) {
                const int kg = quad * 8 + e;
                const float wv = (uv && kg < H) ? w_hh[r * H + kg] : 0.0f;
                Bh[q][ut][e] = (_Float16)wv;
            }
            bias[q][ut] = uv ? (b_ih[r] + b_hh[r]) : 0.0f;
        }
    }

    // ---- staging pointers ----
    const float2* xp = nullptr;
    const uint32_t* sp = nullptr;
    if constexpr (LAYER1) {
        // lane -> (row=l>>2, pos=(l&3)*2): 16 rows x 8 f32 per t
        xp = (const float2*)(x + ((size_t)(b0 + (l >> 2)) * T_TOTAL + tt0) * 8) + (l & 3);
    } else {
        sp = (const uint32_t*)inbuf + ((size_t)tt0 * B_TOTAL + b0) * (D / 2);
    }

    // stage x for absolute step ts into xA[ts&3]
    auto stage = [&](int ts) {
        const bool ok = (ts >= 0) && (ts < T_TOTAL);
        if constexpr (LAYER1) {
            float2 v = {0.0f, 0.0f};
            if (ok) v = *xp;
            xp += sgn * 4;
            if (ok) {
                const uint32_t dw = packf2(v.x, v.y);
                const int row = l >> 2, pos = (l & 3) * 2;
                *(uint32_t*)&xA[ts & 3][row][pos] = dw;            // cur(ts)
                if (ts + 1 < T_TOTAL)
                    *(uint32_t*)&xA[(ts + 1) & 3][row][8 + pos] = dw;  // lag(ts+1)=x[ts]
                if (ts == 0)
                    *(uint32_t*)&xA[0][row][8 + pos] = 0u;         // lag(0)=0
            }
        } else {
            constexpr int TD = 16 * D / 2;    // dwords per t
            if (ok) {
#pragma unroll
                for (int it = 0; it < (TD + 63) / 64; ++it) {
                    const int i = l + 64 * it;
                    if (TD % 64 == 0 || i < TD) {
                        const uint32_t dw = sp[i];
                        const int row = (2 * i) / D;
                        const int col = (2 * i) % D;
                        *(uint32_t*)&xA[ts & 3][row][col] = dw;
                    }
                }
            }
            sp += (ptrdiff_t)sgn * (B_TOTAL * (D / 2));
        }
    };

    stage(tt0);
    stage(tt0 + sgn);

    float cst[UT][4];
#pragma unroll
    for (int ut = 0; ut < UT; ++ut)
#pragma unroll
        for (int r = 0; r < 4; ++r) cst[ut][r] = 0.0f;

    __half* op = nullptr;
    if constexpr (STORE_ALL) {
        op = outbuf + ((size_t)tt0 * B_TOTAL + (b0 + quad * 4)) * (2 * H) + dir * H + ln;
    }

    int tt = tt0;
    for (int t = 0; t < T_TOTAL; ++t) {
        stage(tt + 2 * sgn);

        // ---- gates = bias + x.Wih^T (+ h.Whh^T) ----
        f32x4 acc[4][UT];
#pragma unroll
        for (int q = 0; q < 4; ++q)
#pragma unroll
            for (int ut = 0; ut < UT; ++ut) {
                const float bv = bias[q][ut];
                acc[q][ut][0] = bv; acc[q][ut][1] = bv;
                acc[q][ut][2] = bv; acc[q][ut][3] = bv;
            }
#pragma unroll
        for (int kt = 0; kt < KT; ++kt) {
            const f16x8 ax = *(const f16x8*)&xA[tt & 3][ln][kt * 32 + quad * 8];
#pragma unroll
            for (int q = 0; q < 4; ++q)
#pragma unroll
                for (int ut = 0; ut < UT; ++ut)
                    acc[q][ut] = mfma16(ax, Bx[q][ut][kt], acc[q][ut]);
        }
        wavebar();
        {
            const f16x8 ah = *(const f16x8*)&hA[ln][quad * 8];
#pragma unroll
            for (int q = 0; q < 4; ++q)
#pragma unroll
                for (int ut = 0; ut < UT; ++ut)
                    acc[q][ut] = mfma16(ah, Bh[q][ut], acc[q][ut]);
        }
        wavebar();

        // ---- activations + state update + publish h ----
#pragma unroll
        for (int ut = 0; ut < UT; ++ut) {
            const int u = ut * 16 + ln;
#pragma unroll
            for (int r = 0; r < 4; ++r) {
                const float iv = sigm_(acc[0][ut][r]);
                const float fv = sigm_(acc[1][ut][r]);
                const float gv = tanh_(acc[2][ut][r]);
                const float ov = sigm_(acc[3][ut][r]);
                cst[ut][r] = __builtin_fmaf(fv, cst[ut][r], iv * gv);
                const float hv = ov * tanh_(cst[ut][r]);
                const int row = quad * 4 + r;
                if (u < H) {
                    hA[row][u] = __float2half(hv);
                    if constexpr (STORE_ALL) {
                        op[r * 2 * H + ut * 16] = __float2half(hv);
                    } else {
                        if (t == T_TOTAL - 1)
                            lasth[(size_t)(b0 + row) * H + u] = hv;
                    }
                }
            }
        }
        if constexpr (STORE_ALL) op += (ptrdiff_t)sgn * (B_TOTAL * 2 * H);
        tt += sgn;
    }
}

// L4 backward needed only at t=T-1 (single step from zero state) + FC + sigmoid.
__global__ void final_kernel(const __half* __restrict__ l3out,  // [T][B][20] f16
                             const float* __restrict__ hf4,     // [B][10]
                             const float* __restrict__ w_ih,    // w4b_ih [40][20]
                             const float* __restrict__ b_ih,
                             const float* __restrict__ b_hh,
                             const float* __restrict__ fc_w,    // [20]
                             const float* __restrict__ fc_b,
                             float* __restrict__ out)           // [B]
{
    const int b = blockIdx.x * blockDim.x + threadIdx.x;
    if (b >= B_TOTAL) return;

    float in4[20];
    const __half* p = l3out + (size_t)(T_TOTAL - 1) * (B_TOTAL * 20) + (size_t)b * 20;
#pragma unroll
    for (int i = 0; i < 20; ++i) in4[i] = __half2float(p[i]);

    float z = fc_b[0];
#pragma unroll
    for (int k = 0; k < 10; ++k) z += fc_w[k] * hf4[b * 10 + k];

#pragma unroll
    for (int k = 0; k < 10; ++k) {
        float gi = b_ih[k]      + b_hh[k];
        float gg = b_ih[20 + k] + b_hh[20 + k];
        float go = b_ih[30 + k] + b_hh[30 + k];
#pragma unroll
        for (int i = 0; i < 20; ++i) {
            const float xi = in4[i];
            gi += w_ih[k * 20 + i]        * xi;
            gg += w_ih[(20 + k) * 20 + i] * xi;
            go += w_ih[(30 + k) * 20 + i] * xi;
        }
        const float cc = sigm_(gi) * tanh_(gg);
        const float hb = sigm_(go) * tanh_(cc);
        z += fc_w[10 + k] * hb;
    }
    out[b] = sigm_(z);
}

extern "C" void kernel_launch(void* const* d_in, const int* in_sizes, int n_in,
                              void* d_out, int out_size, void* d_ws, size_t ws_size,
                              hipStream_t stream) {
    const float* x = (const float*)d_in[0];
    auto W = [&](int li, int dr, int k) -> const float* {
        return (const float*)d_in[1 + (li - 1) * 8 + dr * 4 + k];
    };
    const float* fc_w = (const float*)d_in[33];
    const float* fc_b = (const float*)d_in[34];
    float* out = (float*)d_out;

    constexpr size_t MB = 1ull << 20;
    char* w8 = (char*)d_ws;
    __half* A0  = (__half*)w8;                 // [T][B][40] f16, 80 MB
    __half* A1  = (__half*)(w8 + 80 * MB);     // [T][B][40] f16, 80 MB
    float*  HF4 = (float*)(w8 + 160 * MB);     // [B][10] f32

    // L1: D=16 (x+lag via staging), H=20 -> A0
    lstm_mfma<16, 20, true, true><<<dim3(64, 2), 64, 0, stream>>>(
        x, nullptr,
        W(1,0,0), W(1,0,1), W(1,0,2), W(1,0,3),
        W(1,1,0), W(1,1,1), W(1,1,2), W(1,1,3),
        A0, nullptr);

    // L2: D=40, H=20 -> A1
    lstm_mfma<40, 20, false, true><<<dim3(64, 2), 64, 0, stream>>>(
        nullptr, A0,
        W(2,0,0), W(2,0,1), W(2,0,2), W(2,0,3),
        W(2,1,0), W(2,1,1), W(2,1,2), W(2,1,3),
        A1, nullptr);

    // L3: D=40, H=10 -> A0[0,40MB)
    lstm_mfma<40, 10, false, true><<<dim3(64, 2), 64, 0, stream>>>(
        nullptr, A1,
        W(3,0,0), W(3,0,1), W(3,0,2), W(3,0,3),
        W(3,1,0), W(3,1,1), W(3,1,2), W(3,1,3),
        A0, nullptr);

    // L4 forward only: D=20, H=10 -> HF4
    lstm_mfma<20, 10, false, false><<<dim3(64, 1), 64, 0, stream>>>(
        nullptr, A0,
        W(4,0,0), W(4,0,1), W(4,0,2), W(4,0,3),
        W(4,0,0), W(4,0,1), W(4,0,2), W(4,0,3), // dir=1 never launched
        nullptr, HF4);

    // L4 backward single step + FC + sigmoid
    final_kernel<<<dim3(4, 1, 1), 256, 0, stream>>>(
        A0, HF4, W(4,1,0), W(4,1,2), W(4,1,3), fc_w, fc_b, out);
}